// Round 1
// baseline (510.879 us; speedup 1.0000x reference)
//
#include <hip/hip_runtime.h>
#include <hip/hip_bf16.h>

// MoE top-1, E=2: out[t,:] = x[t,:] @ We[e*] + be[e*],  e* = argmax(x[t]@Wg + bg)
// (log(sum_e gate*exp(eo)) == eo[e*] exactly for k=1, gate==1)
//
// ws layout (assumes ws_size >= ~51 MB):
//   [0..8)            : 2 atomic cursors (memset 0 per launch)
//   [4096 ..)         : perm[T]      (int)
//   [4096+64K ..)     : eidx[T]      (int)
//   [4096+128K ..)    : webt bf16 [2][4096][1024]  (16.78 MB)  — We transposed+converted
//   [.. +16.78MB ..)  : xbf  bf16 [T][1024]        (33.55 MB)  — x converted

#define DM 1024
#define DH 4096

typedef __attribute__((ext_vector_type(4))) float f32x4;
typedef __attribute__((ext_vector_type(8))) __bf16 bf16x8;

__device__ __forceinline__ unsigned short f2bf(float f) {
    union { float f; unsigned u; } a; a.f = f;
    unsigned u = a.u;
    u += 0x7fffu + ((u >> 16) & 1u);   // RNE
    return (unsigned short)(u >> 16);
}

__device__ __forceinline__ void gl16(const void* g, void* l) {
    __builtin_amdgcn_global_load_lds(
        (const __attribute__((address_space(1))) unsigned int*)(g),
        (__attribute__((address_space(3))) unsigned int*)(l), 16, 0, 0);
}

// ---------------- gate + x->bf16 convert + counting-sort scatter ----------------
__global__ __launch_bounds__(256) void gate_conv(
    const float* __restrict__ x, const float* __restrict__ Wg,
    const float* __restrict__ bg, int T,
    unsigned short* __restrict__ xbf, int* __restrict__ perm,
    int* __restrict__ eidx, int* __restrict__ cur)
{
    int t = (blockIdx.x * 256 + threadIdx.x) >> 6;
    int lane = threadIdx.x & 63;
    if (t >= T) return;
    const float* xr = x + (size_t)t * DM;
    unsigned short* xw = xbf + (size_t)t * DM;
    int c0 = lane * 16;
    double g0 = 0.0, g1 = 0.0;
#pragma unroll
    for (int j = 0; j < 4; ++j) {
        f32x4 v = *(const f32x4*)(xr + c0 + j * 4);
        unsigned short hh[4];
#pragma unroll
        for (int q = 0; q < 4; ++q) {
            int c = c0 + j * 4 + q;
            hh[q] = f2bf(v[q]);
            g0 += (double)v[q] * (double)Wg[2 * c];
            g1 += (double)v[q] * (double)Wg[2 * c + 1];
        }
        uint2 p;
        p.x = (unsigned)hh[0] | ((unsigned)hh[1] << 16);
        p.y = (unsigned)hh[2] | ((unsigned)hh[3] << 16);
        *(uint2*)(xw + c0 + j * 4) = p;
    }
#pragma unroll
    for (int off = 32; off > 0; off >>= 1) {
        g0 += __shfl_xor(g0, off);
        g1 += __shfl_xor(g1, off);
    }
    if (lane == 0) {
        double L0 = g0 + (double)bg[0];
        double L1 = g1 + (double)bg[1];
        int e = (L1 > L0) ? 1 : 0;   // top_k tie -> lower index
        eidx[t] = e;
        int p;
        if (e == 0) p = atomicAdd(cur, 1);
        else        p = (T - 1) - atomicAdd(cur + 1, 1);
        perm[p] = t;
    }
}

// ---------------- We [2][1024][4096] f32 -> webt [2][4096][1024] bf16 ----------------
__global__ __launch_bounds__(256) void transpose_we(
    const float* __restrict__ We, unsigned short* __restrict__ webt)
{
    __shared__ unsigned short tile[64][72];   // 72-short stride: 16B-aligned rows, decorrelated banks
    int bid = blockIdx.x;
    int e = bid >> 10;
    int r = bid & 1023;
    int kt = r >> 6, ht = r & 63;
    int k0 = kt * 64, h0 = ht * 64;
    int tid = threadIdx.x;

    int k = tid >> 2, hc = tid & 3;
    const float* src = We + ((size_t)e * DM + k0 + k) * DH + h0 + hc * 16;
#pragma unroll
    for (int j = 0; j < 4; ++j) {
        f32x4 v = *(const f32x4*)(src + j * 4);
#pragma unroll
        for (int q = 0; q < 4; ++q)
            tile[hc * 16 + j * 4 + q][k] = f2bf(v[q]);
    }
    __syncthreads();
    int h = tid >> 2, kc = tid & 3;
    unsigned short* dst = webt + ((size_t)e * DH + h0 + h) * DM + k0 + kc * 16;
    *(uint4*)(dst)     = *(const uint4*)&tile[h][kc * 16];
    *(uint4*)(dst + 8) = *(const uint4*)&tile[h][kc * 16 + 8];
}

// ---------------- grouped GEMM: out[perm[i],:] = xbf[perm[i],:] @ webt[e]^T + be[e] ----------------
// 128x128 tile, BK=64, 4 waves (2x2) of 64x64, mfma_f32_16x16x32_bf16.
// LDS linear chunks, T2 XOR-swizzle via pre-swizzled global source (G21).
__global__ __launch_bounds__(256) void moe_gemm(
    const unsigned short* __restrict__ xbf,
    const unsigned short* __restrict__ webt,
    const float* __restrict__ be,
    const int* __restrict__ perm,
    const int* __restrict__ eidx,
    float* __restrict__ out)
{
    __shared__ unsigned short As[128 * 64];
    __shared__ unsigned short Bs[128 * 64];
    int nwg = gridDim.x;
    int bid = blockIdx.x;
    int swz = (bid & 7) * (nwg >> 3) + (bid >> 3);   // XCD swizzle (nwg % 8 == 0)
    int mt = swz >> 5;            // 32 n-tiles
    int nt = swz & 31;
    int m0 = mt * 128, n0 = nt * 128;
    int tid = threadIdx.x, lane = tid & 63, wid = tid >> 6;
    int wm = wid >> 1, wn = wid & 1;

    // staging descriptors: 1024 16B-chunks per tile, 4 per thread.
    // linear LDS chunk c holds element-block [row = c>>3][k8 = (c&7) ^ (row&7)]
    const unsigned short* asrc[4];
    int srow[4], sk8[4];
    unsigned laoff[4];
#pragma unroll
    for (int j = 0; j < 4; ++j) {
        int c = wid * 256 + j * 64 + lane;
        int row = c >> 3;
        int k8 = (c & 7) ^ (row & 7);
        srow[j] = row; sk8[j] = k8;
        asrc[j] = xbf + (size_t)perm[m0 + row] * DM + k8 * 8;
        laoff[j] = (unsigned)(wid * 256 + j * 64) * 16;   // wave-uniform byte base
    }

    int tok[4][4];
#pragma unroll
    for (int mi = 0; mi < 4; ++mi)
#pragma unroll
        for (int r = 0; r < 4; ++r)
            tok[mi][r] = perm[m0 + wm * 64 + mi * 16 + (lane >> 4) * 4 + r];

    int e_lo = eidx[perm[m0]];
    int e_hi = eidx[perm[m0 + 127]];

    for (int e = e_lo; e <= e_hi; ++e) {
        const unsigned short* bsrc[4];
#pragma unroll
        for (int j = 0; j < 4; ++j)
            bsrc[j] = webt + ((size_t)e * DH + n0 + srow[j]) * DM + sk8[j] * 8;

        f32x4 acc[4][4];
#pragma unroll
        for (int mi = 0; mi < 4; ++mi)
#pragma unroll
            for (int ni = 0; ni < 4; ++ni)
                acc[mi][ni] = 0.f;

        for (int kt = 0; kt < DM / 64; ++kt) {
            __syncthreads();                 // previous iter's ds_reads done
#pragma unroll
            for (int j = 0; j < 4; ++j) {
                gl16(asrc[j] + kt * 64, (char*)As + laoff[j]);
                gl16(bsrc[j] + kt * 64, (char*)Bs + laoff[j]);
            }
            __syncthreads();                 // staging visible (compiler drains vmcnt)
#pragma unroll
            for (int kk = 0; kk < 2; ++kk) {
                int g = lane >> 4;
                int rA = wm * 64 + (lane & 15);
                int rB = wn * 64 + (lane & 15);
                int sA = (kk * 4 + g) ^ (rA & 7);
                int sB = (kk * 4 + g) ^ (rB & 7);
                bf16x8 af[4], bfr[4];
#pragma unroll
                for (int mi = 0; mi < 4; ++mi)
                    af[mi] = *(const bf16x8*)&As[(rA + mi * 16) * 64 + sA * 8];
#pragma unroll
                for (int ni = 0; ni < 4; ++ni)
                    bfr[ni] = *(const bf16x8*)&Bs[(rB + ni * 16) * 64 + sB * 8];
#pragma unroll
                for (int mi = 0; mi < 4; ++mi)
#pragma unroll
                    for (int ni = 0; ni < 4; ++ni)
                        acc[mi][ni] = __builtin_amdgcn_mfma_f32_16x16x32_bf16(
                            af[mi], bfr[ni], acc[mi][ni], 0, 0, 0);
            }
        }

        // epilogue: D layout row=(lane>>4)*4+r, col=lane&15  [m89]
        bool ok[4][4];
#pragma unroll
        for (int mi = 0; mi < 4; ++mi)
#pragma unroll
            for (int r = 0; r < 4; ++r)
                ok[mi][r] = (eidx[tok[mi][r]] == e);

        int colb = n0 + wn * 64;
#pragma unroll
        for (int ni = 0; ni < 4; ++ni) {
            int col = colb + ni * 16 + (lane & 15);
            float bv = be[e * DH + col];
#pragma unroll
            for (int mi = 0; mi < 4; ++mi)
#pragma unroll
                for (int r = 0; r < 4; ++r)
                    if (ok[mi][r])
                        out[(size_t)tok[mi][r] * DH + col] = acc[mi][ni][r] + bv;
        }
    }
}

extern "C" void kernel_launch(void* const* d_in, const int* in_sizes, int n_in,
                              void* d_out, int out_size, void* d_ws, size_t ws_size,
                              hipStream_t stream) {
    const float* x  = (const float*)d_in[0];
    const float* Wg = (const float*)d_in[1];
    const float* bg = (const float*)d_in[2];
    const float* We = (const float*)d_in[3];
    const float* be = (const float*)d_in[4];
    float* out = (float*)d_out;
    int T = in_sizes[0] / DM;   // 16384

    char* ws = (char*)d_ws;
    int* cur  = (int*)ws;
    int* perm = (int*)(ws + 4096);
    int* eidx = (int*)(ws + 4096 + 65536);
    unsigned short* webt = (unsigned short*)(ws + 4096 + 2 * 65536);
    unsigned short* xbf  = (unsigned short*)(ws + 4096 + 2 * 65536 + 2 * DH * DM * 2);

    hipMemsetAsync(cur, 0, 8, stream);
    hipLaunchKernelGGL(transpose_we, dim3(2048), dim3(256), 0, stream, We, webt);
    hipLaunchKernelGGL(gate_conv, dim3(T / 4), dim3(256), 0, stream,
                       x, Wg, bg, T, xbf, perm, eidx, cur);
    int nblk = (T / 128) * (DH / 128);
    hipLaunchKernelGGL(moe_gemm, dim3(nblk), dim3(256), 0, stream,
                       xbf, webt, be, perm, eidx, out);
}

// Round 2
// 394.954 us; speedup vs baseline: 1.2935x; 1.2935x over previous
//
#include <hip/hip_runtime.h>
#include <hip/hip_bf16.h>

// MoE top-1, E=2: out[t,:] = x[t,:] @ We[e*] + be[e*],  e* = argmax(x[t]@Wg + bg)
//
// ws layout:
//   [0..8)        : 2 atomic cursors (memset 0 per launch)
//   [4096 ..)     : perm[T] (int)
//   [+64K ..)     : eidx[T] (int)
//   [+128K ..)    : webt bf16 [2][4096][1024]   (We transposed+converted)
//   [+16.78MB ..) : xbf  bf16 [T][1024]         (x converted)

#define DM 1024
#define DH 4096
#define BK 32
#define NK (DM / BK)   // 32 K-tiles

typedef __attribute__((ext_vector_type(4))) float f32x4;
typedef __attribute__((ext_vector_type(8))) __bf16 bf16x8;

__device__ __forceinline__ unsigned short f2bf(float f) {
    union { float f; unsigned u; } a; a.f = f;
    unsigned u = a.u;
    u += 0x7fffu + ((u >> 16) & 1u);   // RNE
    return (unsigned short)(u >> 16);
}

__device__ __forceinline__ void gl16(const unsigned short* g, unsigned short* l) {
    __builtin_amdgcn_global_load_lds(
        (const __attribute__((address_space(1))) unsigned int*)(g),
        (__attribute__((address_space(3))) unsigned int*)(l), 16, 0, 0);
}

// ---------------- fused prep: We transpose+convert  |  gate + x->bf16 + scatter ----------------
__global__ __launch_bounds__(256) void prep(
    const float* __restrict__ x, const float* __restrict__ Wg,
    const float* __restrict__ bg, const float* __restrict__ We, int T,
    unsigned short* __restrict__ xbf, unsigned short* __restrict__ webt,
    int* __restrict__ perm, int* __restrict__ eidx, int* __restrict__ cur)
{
    __shared__ unsigned short tile[64][72];
    int bid = blockIdx.x;
    int tid = threadIdx.x;

    if (bid < 2048) {
        // ---- transpose We [2][1024][4096] f32 -> webt [2][4096][1024] bf16 ----
        int e = bid >> 10;
        int r = bid & 1023;
        int kt = r >> 6, ht = r & 63;
        int k0 = kt * 64, h0 = ht * 64;
        int k = tid >> 2, hc = tid & 3;
        const float* src = We + ((size_t)e * DM + k0 + k) * DH + h0 + hc * 16;
#pragma unroll
        for (int j = 0; j < 4; ++j) {
            f32x4 v = *(const f32x4*)(src + j * 4);
#pragma unroll
            for (int q = 0; q < 4; ++q)
                tile[hc * 16 + j * 4 + q][k] = f2bf(v[q]);
        }
        __syncthreads();
        int h = tid >> 2, kc = tid & 3;
        unsigned short* dst = webt + ((size_t)e * DH + h0 + h) * DM + k0 + kc * 16;
        *(uint4*)(dst)     = *(const uint4*)&tile[h][kc * 16];
        *(uint4*)(dst + 8) = *(const uint4*)&tile[h][kc * 16 + 8];
        return;
    }

    // ---- gate: fp64 logits, argmax, counting-sort scatter; x -> bf16 ----
    int t = (bid - 2048) * 4 + (tid >> 6);
    int lane = tid & 63;
    if (t >= T) return;
    const float* xr = x + (size_t)t * DM;
    unsigned short* xw = xbf + (size_t)t * DM;
    int c0 = lane * 16;
    double g0 = 0.0, g1 = 0.0;
#pragma unroll
    for (int j = 0; j < 4; ++j) {
        f32x4 v = *(const f32x4*)(xr + c0 + j * 4);
        unsigned short hh[4];
#pragma unroll
        for (int q = 0; q < 4; ++q) {
            int c = c0 + j * 4 + q;
            hh[q] = f2bf(v[q]);
            g0 += (double)v[q] * (double)Wg[2 * c];
            g1 += (double)v[q] * (double)Wg[2 * c + 1];
        }
        uint2 p;
        p.x = (unsigned)hh[0] | ((unsigned)hh[1] << 16);
        p.y = (unsigned)hh[2] | ((unsigned)hh[3] << 16);
        *(uint2*)(xw + c0 + j * 4) = p;
    }
#pragma unroll
    for (int off = 32; off > 0; off >>= 1) {
        g0 += __shfl_xor(g0, off);
        g1 += __shfl_xor(g1, off);
    }
    if (lane == 0) {
        double L0 = g0 + (double)bg[0];
        double L1 = g1 + (double)bg[1];
        int e = (L1 > L0) ? 1 : 0;   // tie -> lower index (matches top_k)
        eidx[t] = e;
        int p;
        if (e == 0) p = atomicAdd(cur, 1);
        else        p = (T - 1) - atomicAdd(cur + 1, 1);
        perm[p] = t;
    }
}

// ---------------- grouped GEMM, 256x256 tile, BK=32, 4-deep ring, counted vmcnt ----------------
// 8 waves (2M x 4N), per-wave 128x64 output. T2 swizzle: LDS slot = k8 ^ ((row>>1)&3)
// (2-way bank aliasing = free). global_load_lds dest linear; inverse swizzle on SOURCE (G21).
__global__ __launch_bounds__(512, 2) void moe_gemm(
    const unsigned short* __restrict__ xbf,
    const unsigned short* __restrict__ webt,
    const float* __restrict__ be,
    const int* __restrict__ perm,
    const int* __restrict__ eidx,
    float* __restrict__ out)
{
    __shared__ unsigned short As[4 * 256 * BK];   // 64 KiB
    __shared__ unsigned short Bs[4 * 256 * BK];   // 64 KiB
    const int nwg = gridDim.x;                    // 1024, %8==0
    const int bid = blockIdx.x;
    const int swz = (bid & 7) * (nwg >> 3) + (bid >> 3);
    const int mt = swz >> 4, nt = swz & 15;       // 64 m-tiles x 16 n-tiles
    const int m0 = mt * 256, n0 = nt * 256;
    const int tid = threadIdx.x, lane = tid & 63, wid = tid >> 6;
    const int wm = wid >> 2, wn = wid & 3;

    // staging descriptors: 1024 16B-chunks per operand per K-tile; 2 A + 2 B per thread.
    // linear LDS chunk c = [row = c>>2][slot = c&3]; slot holds k-block (slot ^ ((row>>1)&3)).
    const unsigned short *aptr0, *aptr1;
    size_t boff0, boff1;
    unsigned lofs0, lofs1;
    {
        int c0 = wid * 128 + lane, c1 = c0 + 64;
        int r0 = c0 >> 2, k0 = (c0 & 3) ^ ((r0 >> 1) & 3);
        int r1 = c1 >> 2, k1 = (c1 & 3) ^ ((r1 >> 1) & 3);
        aptr0 = xbf + (size_t)perm[m0 + r0] * DM + k0 * 8;
        aptr1 = xbf + (size_t)perm[m0 + r1] * DM + k1 * 8;
        boff0 = (size_t)(n0 + r0) * DM + k0 * 8;
        boff1 = (size_t)(n0 + r1) * DM + k1 * 8;
        lofs0 = (unsigned)(wid * 128) * 8;        // wave-uniform LDS short-offset
        lofs1 = (unsigned)(wid * 128 + 64) * 8;
    }

    // fragment read offsets (swizzled); slot constant across mi/ni (stride 16 rows ≡ 0 mod 4<<1)
    const int rA = wm * 128 + (lane & 15);
    const int rB = wn * 64 + (lane & 15);
    const int idxA = rA * BK + (((lane >> 4) ^ ((rA >> 1) & 3)) * 8);
    const int idxB = rB * BK + (((lane >> 4) ^ ((rB >> 1) & 3)) * 8);

    const int e_lo = eidx[perm[m0]];
    const int e_hi = eidx[perm[m0 + 255]];

    for (int e = e_lo; e <= e_hi; ++e) {
        const unsigned short* bb = webt + (size_t)e * DH * DM;

        // prologue: stage K-tiles 0 and 1 (8 loads -> vmcnt 8)
#pragma unroll
        for (int u = 0; u < 2; ++u) {
            unsigned short* ab = As + u * (256 * BK);
            unsigned short* bbf = Bs + u * (256 * BK);
            gl16(aptr0 + u * BK, ab + lofs0);
            gl16(aptr1 + u * BK, ab + lofs1);
            gl16(bb + boff0 + u * BK, bbf + lofs0);
            gl16(bb + boff1 + u * BK, bbf + lofs1);
        }

        f32x4 acc[8][4];
#pragma unroll
        for (int mi = 0; mi < 8; ++mi)
#pragma unroll
            for (int ni = 0; ni < 4; ++ni) acc[mi][ni] = 0.f;

        auto body = [&](int kt, bool pf) {
            __builtin_amdgcn_sched_barrier(0);
            __builtin_amdgcn_s_barrier();
            __builtin_amdgcn_sched_barrier(0);
            const unsigned short* ab  = As + (kt & 3) * (256 * BK);
            const unsigned short* bbf = Bs + (kt & 3) * (256 * BK);
            const int pt = kt + 2;
            unsigned short* pab = As + (pt & 3) * (256 * BK);
            unsigned short* pbb = Bs + (pt & 3) * (256 * BK);

            // phase 1: frags A0-3, B0-3; issue next A-tile loads; 16 MFMA
            bf16x8 af[4], bfr[4];
#pragma unroll
            for (int mi = 0; mi < 4; ++mi) af[mi] = *(const bf16x8*)(ab + idxA + mi * 16 * BK);
#pragma unroll
            for (int ni = 0; ni < 4; ++ni) bfr[ni] = *(const bf16x8*)(bbf + idxB + ni * 16 * BK);
            if (pf) {
                gl16(aptr0 + pt * BK, pab + lofs0);
                gl16(aptr1 + pt * BK, pab + lofs1);
            }
            __builtin_amdgcn_s_setprio(1);
#pragma unroll
            for (int mi = 0; mi < 4; ++mi)
#pragma unroll
                for (int ni = 0; ni < 4; ++ni)
                    acc[mi][ni] = __builtin_amdgcn_mfma_f32_16x16x32_bf16(
                        af[mi], bfr[ni], acc[mi][ni], 0, 0, 0);
            __builtin_amdgcn_s_setprio(0);

            // phase 2: frags A4-7; issue next B-tile loads; 16 MFMA
            bf16x8 af2[4];
#pragma unroll
            for (int mi = 0; mi < 4; ++mi) af2[mi] = *(const bf16x8*)(ab + idxA + (mi + 4) * 16 * BK);
            if (pf) {
                gl16(bb + boff0 + pt * BK, pbb + lofs0);
                gl16(bb + boff1 + pt * BK, pbb + lofs1);
            }
            __builtin_amdgcn_s_setprio(1);
#pragma unroll
            for (int mi = 0; mi < 4; ++mi)
#pragma unroll
                for (int ni = 0; ni < 4; ++ni)
                    acc[mi + 4][ni] = __builtin_amdgcn_mfma_f32_16x16x32_bf16(
                        af2[mi], bfr[ni], acc[mi + 4][ni], 0, 0, 0);
            __builtin_amdgcn_s_setprio(0);
        };

        // main loop: counted vmcnt(4) — K-tile kt landed, kt+1 (4 loads) stays in flight
#pragma unroll 1
        for (int kt = 0; kt < NK - 1; ++kt) {
            asm volatile("s_waitcnt vmcnt(4)" ::: "memory");
            body(kt, kt + 2 < NK);
        }
        asm volatile("s_waitcnt vmcnt(0)" ::: "memory");
        body(NK - 1, false);

        // epilogue: D row=(lane>>4)*4+r, col=lane&15 [m89]
        const int colc = n0 + wn * 64 + (lane & 15);
        float bev[4];
#pragma unroll
        for (int ni = 0; ni < 4; ++ni) bev[ni] = be[e * DH + colc + ni * 16];
        const int rb = m0 + wm * 128 + (lane >> 4) * 4;
#pragma unroll
        for (int mi = 0; mi < 8; ++mi) {
#pragma unroll
            for (int r = 0; r < 4; ++r) {
                int tk = perm[rb + mi * 16 + r];
                if (e_lo == e_hi || eidx[tk] == e) {
                    float* orow = out + (size_t)tk * DH + colc;
#pragma unroll
                    for (int ni = 0; ni < 4; ++ni)
                        orow[ni * 16] = acc[mi][ni][r] + bev[ni];
                }
            }
        }
    }
}

extern "C" void kernel_launch(void* const* d_in, const int* in_sizes, int n_in,
                              void* d_out, int out_size, void* d_ws, size_t ws_size,
                              hipStream_t stream) {
    const float* x  = (const float*)d_in[0];
    const float* Wg = (const float*)d_in[1];
    const float* bg = (const float*)d_in[2];
    const float* We = (const float*)d_in[3];
    const float* be = (const float*)d_in[4];
    float* out = (float*)d_out;
    int T = in_sizes[0] / DM;   // 16384

    char* ws = (char*)d_ws;
    int* cur  = (int*)ws;
    int* perm = (int*)(ws + 4096);
    int* eidx = (int*)(ws + 4096 + 65536);
    unsigned short* webt = (unsigned short*)(ws + 4096 + 2 * 65536);
    unsigned short* xbf  = (unsigned short*)(ws + 4096 + 2 * 65536 + (size_t)2 * DH * DM * 2);

    hipMemsetAsync(cur, 0, 8, stream);
    hipLaunchKernelGGL(prep, dim3(2048 + T / 4), dim3(256), 0, stream,
                       x, Wg, bg, We, T, xbf, webt, perm, eidx, cur);
    int nblk = (T / 256) * (DH / 256);   // 64 * 16 = 1024
    hipLaunchKernelGGL(moe_gemm, dim3(nblk), dim3(512), 0, stream,
                       xbf, webt, be, perm, eidx, out);
}

// Round 3
// 261.590 us; speedup vs baseline: 1.9530x; 1.5098x over previous
//
#include <hip/hip_runtime.h>
#include <hip/hip_bf16.h>

// MoE top-1, E=2: out[t,:] = x[t,:] @ We[e*] + be[e*],  e* = argmax(x[t]@Wg + bg)
//
// moe_gemm: 256x256 tile, 8 waves (2Mx4N), K-step 32, 4-deep LDS rings,
// 2 phases per K-step {ds_read frags | stage 1 half-tile | bar | lgkm(0) |
// setprio+16 MFMA | bar(+counted vmcnt at odd phases)}.
// Stage lead: A(s+3)/B(s+3) issued at phases of K-step s (ring-liveness safe:
// A(s-1) last read in phase(s-1,1), barrier-separated). vmcnt(6) => arrived
// through half-tile 2s+4 >= needed 2s+3. Tail: vmcnt 6,4,0 peeled.

#define DM 1024
#define DH 4096
#define KS 32
#define NS (DM / KS)   // 32 K-steps

typedef __attribute__((ext_vector_type(4))) float f32x4;
typedef __attribute__((ext_vector_type(8))) __bf16 bf16x8;

__device__ __forceinline__ unsigned short f2bf(float f) {
    union { float f; unsigned u; } a; a.f = f;
    unsigned u = a.u;
    u += 0x7fffu + ((u >> 16) & 1u);   // RNE
    return (unsigned short)(u >> 16);
}

__device__ __forceinline__ void gl16(const unsigned short* g, unsigned short* l) {
    __builtin_amdgcn_global_load_lds(
        (const __attribute__((address_space(1))) unsigned int*)(g),
        (__attribute__((address_space(3))) unsigned int*)(l), 16, 0, 0);
}

// ---------------- prep: We transpose (bid<512) | gate+convert+scatter (bid>=512) ----------------
__global__ __launch_bounds__(1024) void prep(
    const float* __restrict__ x, const float* __restrict__ Wg,
    const float* __restrict__ bg, const float* __restrict__ We, int T,
    unsigned short* __restrict__ xbf, unsigned short* __restrict__ webt,
    int* __restrict__ perm, int* __restrict__ eidx, int* __restrict__ cur)
{
    int bid = blockIdx.x, tid = threadIdx.x;

    if (bid < 512) {
        // ---- We [2][1024][4096] f32 -> webt [2][4096][1024] bf16, 4 64x64 tiles/block ----
        __shared__ unsigned short tile[4][64][72];
        int sub = tid >> 8, t2 = tid & 255;
        int g = bid * 4 + sub;
        int e = g >> 10, rr = g & 1023, kt = rr >> 6, ht = rr & 63;
        int k0 = kt * 64, h0 = ht * 64;
        int k = t2 >> 2, hc = t2 & 3;
        const float* src = We + ((size_t)e * DM + k0 + k) * DH + h0 + hc * 16;
#pragma unroll
        for (int j = 0; j < 4; ++j) {
            f32x4 v = *(const f32x4*)(src + j * 4);
#pragma unroll
            for (int q = 0; q < 4; ++q)
                tile[sub][hc * 16 + j * 4 + q][k] = f2bf(v[q]);
        }
        __syncthreads();
        int h = t2 >> 2, kc = t2 & 3;
        unsigned short* dst = webt + ((size_t)e * DH + h0 + h) * DM + k0 + kc * 16;
        *(uint4*)(dst)     = *(const uint4*)&tile[sub][h][kc * 16];
        *(uint4*)(dst + 8) = *(const uint4*)&tile[sub][h][kc * 16 + 8];
        return;
    }

    // ---- gate: 64 tokens/block, 16 waves x 4 tokens; 2 atomics/block (G12) ----
    __shared__ unsigned char eL[64];
    int gb = bid - 512;                 // 0..255
    int lane = tid & 63, w = tid >> 6;  // 16 waves
    float wgv[32];                      // Wg rows 2c,2c+1 for this lane's 16 cols
#pragma unroll
    for (int j = 0; j < 8; ++j)
        *(f32x4*)&wgv[j * 4] = *(const f32x4*)(Wg + lane * 32 + j * 4);
    float bg0 = bg[0], bg1 = bg[1];
    int t0 = gb * 64 + w * 4;
#pragma unroll
    for (int tl = 0; tl < 4; ++tl) {
        int t = t0 + tl;
        const float* xr = x + (size_t)t * DM + lane * 16;
        double g0 = 0.0, g1 = 0.0;
        unsigned hw[8];
#pragma unroll
        for (int j = 0; j < 4; ++j) {
            f32x4 v = *(const f32x4*)(xr + j * 4);
#pragma unroll
            for (int q = 0; q < 4; ++q) {
                g0 += (double)v[q] * (double)wgv[2 * (j * 4 + q)];
                g1 += (double)v[q] * (double)wgv[2 * (j * 4 + q) + 1];
            }
            hw[j * 2]     = (unsigned)f2bf(v[0]) | ((unsigned)f2bf(v[1]) << 16);
            hw[j * 2 + 1] = (unsigned)f2bf(v[2]) | ((unsigned)f2bf(v[3]) << 16);
        }
        unsigned short* xw = xbf + (size_t)t * DM + lane * 16;
        uint4 u0; u0.x = hw[0]; u0.y = hw[1]; u0.z = hw[2]; u0.w = hw[3];
        uint4 u1; u1.x = hw[4]; u1.y = hw[5]; u1.z = hw[6]; u1.w = hw[7];
        *(uint4*)(xw)     = u0;
        *(uint4*)(xw + 8) = u1;
#pragma unroll
        for (int off = 32; off; off >>= 1) {
            g0 += __shfl_xor(g0, off);
            g1 += __shfl_xor(g1, off);
        }
        if (lane == 0) {
            int ee = ((g1 + (double)bg1) > (g0 + (double)bg0)) ? 1 : 0;  // tie -> e0
            eidx[t] = ee;
            eL[w * 4 + tl] = (unsigned char)ee;
        }
    }
    __syncthreads();
    if (w == 0) {
        int myE = eL[lane];
        unsigned long long m1 = __ballot(myE != 0);
        int tot1 = __popcll(m1);
        int b0 = 0, b1 = 0;
        if (lane == 0) {
            b0 = atomicAdd(cur, 64 - tot1);
            b1 = atomicAdd(cur + 1, tot1);
        }
        b0 = __shfl(b0, 0);
        b1 = __shfl(b1, 0);
        unsigned long long lm = (1ull << lane) - 1ull;
        int rank = __popcll((myE ? m1 : ~m1) & lm);
        int dstp = myE ? (T - b1 - tot1 + rank) : (b0 + rank);
        perm[dstp] = gb * 64 + lane;
    }
}

// ---------------- grouped GEMM, 8-phase schedule ----------------
__global__ __launch_bounds__(512, 2) void moe_gemm(
    const unsigned short* __restrict__ xbf,
    const unsigned short* __restrict__ webt,
    const float* __restrict__ be,
    const int* __restrict__ perm,
    const int* __restrict__ eidx,
    float* __restrict__ out)
{
    __shared__ unsigned short As[4][256 * KS];   // 4 x 16 KiB
    __shared__ unsigned short Bs[4][256 * KS];   // 4 x 16 KiB
    const int nwg = gridDim.x;                   // 1024, %8==0
    const int bid = blockIdx.x;
    const int swz = (bid & 7) * (nwg >> 3) + (bid >> 3);
    const int mt = swz >> 4, nt = swz & 15;      // 64 m-tiles x 16 n-tiles
    const int m0 = mt * 256, n0 = nt * 256;
    const int tid = threadIdx.x, lane = tid & 63, wid = tid >> 6;
    const int wm = wid >> 2, wn = wid & 3;

    // staging: 1024 granules(16B) per region; granule c=[row=c>>2][phys=c&3],
    // logical k8 = phys ^ (row&3)  (inverse swizzle on SOURCE, linear LDS dest)
    const unsigned short* aptr[2];
    size_t bofs[2];
    unsigned lofs[2];
#pragma unroll
    for (int j = 0; j < 2; ++j) {
        int c = wid * 128 + j * 64 + lane;
        int row = c >> 2, k8 = (c & 3) ^ (row & 3);
        aptr[j] = xbf + (size_t)perm[m0 + row] * DM + k8 * 8;
        bofs[j] = (size_t)(n0 + row) * DM + k8 * 8;
        lofs[j] = (unsigned)(wid * 128 + j * 64) * 8;   // wave-uniform (shorts)
    }

    // fragment offsets (swizzled read): slot = (lane>>4) ^ (row&3); row&3 const over mi/ni
    const int rA = wm * 128 + (lane & 15);
    const int rB = wn * 64 + (lane & 15);
    const int offA = rA * KS + (((lane >> 4) ^ (rA & 3)) * 8);
    const int offB = rB * KS + (((lane >> 4) ^ (rB & 3)) * 8);

    const int e_lo = eidx[perm[m0]];
    const int e_hi = eidx[perm[m0 + 255]];

    for (int e = e_lo; e <= e_hi; ++e) {
        const unsigned short* wb = webt + (size_t)e * DH * DM;

        // prologue: stage halves A0,B0,A1,B1,A2,B2 (12 loads), wait first 2
#pragma unroll
        for (int s = 0; s < 3; ++s) {
#pragma unroll
            for (int j = 0; j < 2; ++j) gl16(aptr[j] + s * KS, As[s] + lofs[j]);
#pragma unroll
            for (int j = 0; j < 2; ++j) gl16(wb + bofs[j] + s * KS, Bs[s] + lofs[j]);
        }
        f32x4 acc[8][4];
#pragma unroll
        for (int mi = 0; mi < 8; ++mi)
#pragma unroll
            for (int ni = 0; ni < 4; ++ni) acc[mi][ni] = 0.f;
        asm volatile("s_waitcnt vmcnt(8)" ::: "memory");
        __builtin_amdgcn_s_barrier();

        bf16x8 bfr[4];
        auto phase = [&](int s, int mh, bool doStage, int wcnt) {
            const unsigned short* areg = As[s & 3];
            bf16x8 af[4];
            if (mh == 0) {
                const unsigned short* breg = Bs[s & 3];
#pragma unroll
                for (int ni = 0; ni < 4; ++ni)
                    bfr[ni] = *(const bf16x8*)(breg + offB + ni * 16 * KS);
#pragma unroll
                for (int mi = 0; mi < 4; ++mi)
                    af[mi] = *(const bf16x8*)(areg + offA + mi * 16 * KS);
            } else {
#pragma unroll
                for (int mi = 0; mi < 4; ++mi)
                    af[mi] = *(const bf16x8*)(areg + offA + (mi + 4) * 16 * KS);
            }
            if (doStage) {
                int t = s + 3;
                if (mh == 0) {
                    unsigned short* dreg = As[t & 3];
#pragma unroll
                    for (int j = 0; j < 2; ++j) gl16(aptr[j] + t * KS, dreg + lofs[j]);
                } else {
                    unsigned short* dreg = Bs[t & 3];
#pragma unroll
                    for (int j = 0; j < 2; ++j) gl16(wb + bofs[j] + t * KS, dreg + lofs[j]);
                }
            }
            __builtin_amdgcn_sched_barrier(0);
            __builtin_amdgcn_s_barrier();
            asm volatile("s_waitcnt lgkmcnt(0)" ::: "memory");
            __builtin_amdgcn_sched_barrier(0);
            __builtin_amdgcn_s_setprio(1);
            const int mb = mh * 4;
#pragma unroll
            for (int mi = 0; mi < 4; ++mi)
#pragma unroll
                for (int ni = 0; ni < 4; ++ni)
                    acc[mb + mi][ni] = __builtin_amdgcn_mfma_f32_16x16x32_bf16(
                        af[mi], bfr[ni], acc[mb + mi][ni], 0, 0, 0);
            __builtin_amdgcn_s_setprio(0);
            __builtin_amdgcn_sched_barrier(0);
            if (wcnt == 6)      asm volatile("s_waitcnt vmcnt(6)" ::: "memory");
            else if (wcnt == 4) asm volatile("s_waitcnt vmcnt(4)" ::: "memory");
            else if (wcnt == 0) asm volatile("s_waitcnt vmcnt(0)" ::: "memory");
            __builtin_amdgcn_s_barrier();
            __builtin_amdgcn_sched_barrier(0);
        };

#pragma unroll 1
        for (int it = 0; it < 7; ++it) {
            int sb = it * 4;
#pragma unroll
            for (int q = 0; q < 4; ++q) {
                phase(sb + q, 0, true, -1);
                phase(sb + q, 1, true, 6);
            }
        }
        // tail: K-steps 28..31 (stages A31,B31 only; waits 6,4,0)
        phase(28, 0, true,  -1);
        phase(28, 1, true,   6);
        phase(29, 0, false, -1);
        phase(29, 1, false,  4);
        phase(30, 0, false, -1);
        phase(30, 1, false,  0);
        phase(31, 0, false, -1);
        phase(31, 1, false, -1);

        // epilogue: D row=(lane>>4)*4+r, col=lane&15 [m89]
        const int colc = n0 + wn * 64 + (lane & 15);
        float bev[4];
#pragma unroll
        for (int ni = 0; ni < 4; ++ni) bev[ni] = be[e * DH + colc + ni * 16];
        const int rb = m0 + wm * 128 + (lane >> 4) * 4;
#pragma unroll
        for (int mi = 0; mi < 8; ++mi) {
#pragma unroll
            for (int r = 0; r < 4; ++r) {
                int tk = perm[rb + mi * 16 + r];
                if (e_lo == e_hi || eidx[tk] == e) {
                    float* orow = out + (size_t)tk * DH + colc;
#pragma unroll
                    for (int ni = 0; ni < 4; ++ni)
                        orow[ni * 16] = acc[mi][ni][r] + bev[ni];
                }
            }
        }
    }
}

extern "C" void kernel_launch(void* const* d_in, const int* in_sizes, int n_in,
                              void* d_out, int out_size, void* d_ws, size_t ws_size,
                              hipStream_t stream) {
    const float* x  = (const float*)d_in[0];
    const float* Wg = (const float*)d_in[1];
    const float* bg = (const float*)d_in[2];
    const float* We = (const float*)d_in[3];
    const float* be = (const float*)d_in[4];
    float* out = (float*)d_out;
    int T = in_sizes[0] / DM;   // 16384

    char* ws = (char*)d_ws;
    int* cur  = (int*)ws;
    int* perm = (int*)(ws + 4096);
    int* eidx = (int*)(ws + 4096 + 65536);
    unsigned short* webt = (unsigned short*)(ws + 4096 + 2 * 65536);
    unsigned short* xbf  = (unsigned short*)(ws + 4096 + 2 * 65536 + (size_t)2 * DH * DM * 2);

    hipMemsetAsync(cur, 0, 8, stream);
    hipLaunchKernelGGL(prep, dim3(512 + T / 64), dim3(1024), 0, stream,
                       x, Wg, bg, We, T, xbf, webt, perm, eidx, cur);
    int nblk = (T / 256) * (DH / 256);   // 64 * 16 = 1024
    hipLaunchKernelGGL(moe_gemm, dim3(nblk), dim3(512), 0, stream,
                       xbf, webt, be, perm, eidx, out);
}

// Round 4
// 252.459 us; speedup vs baseline: 2.0236x; 1.0362x over previous
//
#include <hip/hip_runtime.h>
#include <hip/hip_bf16.h>

// MoE top-1, E=2: out[t,:] = x[t,:] @ We[e*] + be[e*],  e* = argmax(x[t]@Wg + bg)
//
// moe_gemm: 256x256 tile, 8 waves (2Mx4N), K-step 32, 4-deep LDS rings,
// 2 phases per K-step {ds_read frags | stage 1 half-tile | bar | lgkm(0) |
// setprio+16 MFMA | bar(+counted vmcnt at odd phases)}.
// Swizzle: f(row)=(row>>1)&3 (R2-verified zero-conflict: (row&1,slot) covers
// all 8 bank-groups evenly over any 16 consecutive rows; rows step by 16 in
// fragment reads so the slot is mi/ni-invariant).

#define DM 1024
#define DH 4096
#define KS 32
#define NS (DM / KS)   // 32 K-steps

typedef __attribute__((ext_vector_type(4))) float f32x4;
typedef __attribute__((ext_vector_type(8))) __bf16 bf16x8;

__device__ __forceinline__ unsigned short f2bf(float f) {
    union { float f; unsigned u; } a; a.f = f;
    unsigned u = a.u;
    u += 0x7fffu + ((u >> 16) & 1u);   // RNE
    return (unsigned short)(u >> 16);
}

__device__ __forceinline__ void gl16(const unsigned short* g, unsigned short* l) {
    __builtin_amdgcn_global_load_lds(
        (const __attribute__((address_space(1))) unsigned int*)(g),
        (__attribute__((address_space(3))) unsigned int*)(l), 16, 0, 0);
}

// ---------------- prep: We transpose (bid<512) | gate+convert+scatter (bid>=512) ----------------
__global__ __launch_bounds__(1024) void prep(
    const float* __restrict__ x, const float* __restrict__ Wg,
    const float* __restrict__ bg, const float* __restrict__ We, int T,
    unsigned short* __restrict__ xbf, unsigned short* __restrict__ webt,
    int* __restrict__ perm, int* __restrict__ eidx, int* __restrict__ cur)
{
    int bid = blockIdx.x, tid = threadIdx.x;

    if (bid < 512) {
        // ---- We [2][1024][4096] f32 -> webt [2][4096][1024] bf16, 4 64x64 tiles/block ----
        __shared__ unsigned short tile[4][64][72];
        int sub = tid >> 8, t2 = tid & 255;
        int g = bid * 4 + sub;
        int e = g >> 10, rr = g & 1023, kt = rr >> 6, ht = rr & 63;
        int k0 = kt * 64, h0 = ht * 64;
        int k = t2 >> 2, hc = t2 & 3;
        const float* src = We + ((size_t)e * DM + k0 + k) * DH + h0 + hc * 16;
#pragma unroll
        for (int j = 0; j < 4; ++j) {
            f32x4 v = *(const f32x4*)(src + j * 4);
#pragma unroll
            for (int q = 0; q < 4; ++q)
                tile[sub][hc * 16 + j * 4 + q][k] = f2bf(v[q]);
        }
        __syncthreads();
        int h = t2 >> 2, kc = t2 & 3;
        unsigned short* dst = webt + ((size_t)e * DH + h0 + h) * DM + k0 + kc * 16;
        *(uint4*)(dst)     = *(const uint4*)&tile[sub][h][kc * 16];
        *(uint4*)(dst + 8) = *(const uint4*)&tile[sub][h][kc * 16 + 8];
        return;
    }

    // ---- gate: 64 tokens/block, 16 waves x 4 tokens; 2 atomics/block (G12) ----
    __shared__ unsigned char eL[64];
    int gb = bid - 512;                 // 0..255
    int lane = tid & 63, w = tid >> 6;  // 16 waves
    float wgv[32];                      // Wg rows 2c,2c+1 for this lane's 16 cols
#pragma unroll
    for (int j = 0; j < 8; ++j)
        *(f32x4*)&wgv[j * 4] = *(const f32x4*)(Wg + lane * 32 + j * 4);
    float bg0 = bg[0], bg1 = bg[1];
    int t0 = gb * 64 + w * 4;
#pragma unroll
    for (int tl = 0; tl < 4; ++tl) {
        int t = t0 + tl;
        const float* xr = x + (size_t)t * DM + lane * 16;
        double g0 = 0.0, g1 = 0.0;
        unsigned hw[8];
#pragma unroll
        for (int j = 0; j < 4; ++j) {
            f32x4 v = *(const f32x4*)(xr + j * 4);
#pragma unroll
            for (int q = 0; q < 4; ++q) {
                g0 += (double)v[q] * (double)wgv[2 * (j * 4 + q)];
                g1 += (double)v[q] * (double)wgv[2 * (j * 4 + q) + 1];
            }
            hw[j * 2]     = (unsigned)f2bf(v[0]) | ((unsigned)f2bf(v[1]) << 16);
            hw[j * 2 + 1] = (unsigned)f2bf(v[2]) | ((unsigned)f2bf(v[3]) << 16);
        }
        unsigned short* xw = xbf + (size_t)t * DM + lane * 16;
        uint4 u0; u0.x = hw[0]; u0.y = hw[1]; u0.z = hw[2]; u0.w = hw[3];
        uint4 u1; u1.x = hw[4]; u1.y = hw[5]; u1.z = hw[6]; u1.w = hw[7];
        *(uint4*)(xw)     = u0;
        *(uint4*)(xw + 8) = u1;
#pragma unroll
        for (int off = 32; off; off >>= 1) {
            g0 += __shfl_xor(g0, off);
            g1 += __shfl_xor(g1, off);
        }
        if (lane == 0) {
            int ee = ((g1 + (double)bg1) > (g0 + (double)bg0)) ? 1 : 0;  // tie -> e0
            eidx[t] = ee;
            eL[w * 4 + tl] = (unsigned char)ee;
        }
    }
    __syncthreads();
    if (w == 0) {
        int myE = eL[lane];
        unsigned long long m1 = __ballot(myE != 0);
        int tot1 = __popcll(m1);
        int b0 = 0, b1 = 0;
        if (lane == 0) {
            b0 = atomicAdd(cur, 64 - tot1);
            b1 = atomicAdd(cur + 1, tot1);
        }
        b0 = __shfl(b0, 0);
        b1 = __shfl(b1, 0);
        unsigned long long lm = (1ull << lane) - 1ull;
        int rank = __popcll((myE ? m1 : ~m1) & lm);
        int dstp = myE ? (T - b1 - tot1 + rank) : (b0 + rank);
        perm[dstp] = gb * 64 + lane;
    }
}

// ---------------- grouped GEMM, 8-phase schedule ----------------
__global__ __launch_bounds__(512, 2) void moe_gemm(
    const unsigned short* __restrict__ xbf,
    const unsigned short* __restrict__ webt,
    const float* __restrict__ be,
    const int* __restrict__ perm,
    const int* __restrict__ eidx,
    float* __restrict__ out)
{
    __shared__ unsigned short As[4][256 * KS];   // 4 x 16 KiB
    __shared__ unsigned short Bs[4][256 * KS];   // 4 x 16 KiB
    const int nwg = gridDim.x;                   // 1024, %8==0
    const int bid = blockIdx.x;
    const int swz = (bid & 7) * (nwg >> 3) + (bid >> 3);
    const int mt = swz >> 4, nt = swz & 15;      // 64 m-tiles x 16 n-tiles
    const int m0 = mt * 256, n0 = nt * 256;
    const int tid = threadIdx.x, lane = tid & 63, wid = tid >> 6;
    const int wm = wid >> 2, wn = wid & 3;

    // staging: 1024 granules(16B) per region; granule c=[row=c>>2][phys=c&3],
    // logical k8 = phys ^ ((row>>1)&3)  (inverse swizzle on SOURCE, linear LDS dest)
    const unsigned short* aptr[2];
    size_t bofs[2];
    unsigned lofs[2];
#pragma unroll
    for (int j = 0; j < 2; ++j) {
        int c = wid * 128 + j * 64 + lane;
        int row = c >> 2, k8 = (c & 3) ^ ((row >> 1) & 3);
        aptr[j] = xbf + (size_t)perm[m0 + row] * DM + k8 * 8;
        bofs[j] = (size_t)(n0 + row) * DM + k8 * 8;
        lofs[j] = (unsigned)(wid * 128 + j * 64) * 8;   // wave-uniform (shorts)
    }

    // fragment offsets (swizzled read): slot = (lane>>4) ^ ((row>>1)&3); invariant over mi/ni
    const int rA = wm * 128 + (lane & 15);
    const int rB = wn * 64 + (lane & 15);
    const int offA = rA * KS + (((lane >> 4) ^ ((rA >> 1) & 3)) * 8);
    const int offB = rB * KS + (((lane >> 4) ^ ((rB >> 1) & 3)) * 8);

    const int e_lo = eidx[perm[m0]];
    const int e_hi = eidx[perm[m0 + 255]];

    for (int e = e_lo; e <= e_hi; ++e) {
        const unsigned short* wb = webt + (size_t)e * DH * DM;

        // prologue: stage halves A0,B0,A1,B1,A2,B2 (12 loads), wait first 4
#pragma unroll
        for (int s = 0; s < 3; ++s) {
#pragma unroll
            for (int j = 0; j < 2; ++j) gl16(aptr[j] + s * KS, As[s] + lofs[j]);
#pragma unroll
            for (int j = 0; j < 2; ++j) gl16(wb + bofs[j] + s * KS, Bs[s] + lofs[j]);
        }
        f32x4 acc[8][4];
#pragma unroll
        for (int mi = 0; mi < 8; ++mi)
#pragma unroll
            for (int ni = 0; ni < 4; ++ni) acc[mi][ni] = 0.f;
        asm volatile("s_waitcnt vmcnt(8)" ::: "memory");
        __builtin_amdgcn_s_barrier();

        bf16x8 bfr[4];
        auto phase = [&](int s, int mh, bool doStage, int wcnt) {
            const unsigned short* areg = As[s & 3];
            bf16x8 af[4];
            if (mh == 0) {
                const unsigned short* breg = Bs[s & 3];
#pragma unroll
                for (int ni = 0; ni < 4; ++ni)
                    bfr[ni] = *(const bf16x8*)(breg + offB + ni * 16 * KS);
#pragma unroll
                for (int mi = 0; mi < 4; ++mi)
                    af[mi] = *(const bf16x8*)(areg + offA + mi * 16 * KS);
            } else {
#pragma unroll
                for (int mi = 0; mi < 4; ++mi)
                    af[mi] = *(const bf16x8*)(areg + offA + (mi + 4) * 16 * KS);
            }
            if (doStage) {
                int t = s + 3;
                if (mh == 0) {
                    unsigned short* dreg = As[t & 3];
#pragma unroll
                    for (int j = 0; j < 2; ++j) gl16(aptr[j] + t * KS, dreg + lofs[j]);
                } else {
                    unsigned short* dreg = Bs[t & 3];
#pragma unroll
                    for (int j = 0; j < 2; ++j) gl16(wb + bofs[j] + t * KS, dreg + lofs[j]);
                }
            }
            __builtin_amdgcn_sched_barrier(0);
            __builtin_amdgcn_s_barrier();
            asm volatile("s_waitcnt lgkmcnt(0)" ::: "memory");
            __builtin_amdgcn_sched_barrier(0);
            __builtin_amdgcn_s_setprio(1);
            const int mb = mh * 4;
#pragma unroll
            for (int mi = 0; mi < 4; ++mi)
#pragma unroll
                for (int ni = 0; ni < 4; ++ni)
                    acc[mb + mi][ni] = __builtin_amdgcn_mfma_f32_16x16x32_bf16(
                        af[mi], bfr[ni], acc[mb + mi][ni], 0, 0, 0);
            __builtin_amdgcn_s_setprio(0);
            __builtin_amdgcn_sched_barrier(0);
            if (wcnt == 6)      asm volatile("s_waitcnt vmcnt(6)" ::: "memory");
            else if (wcnt == 4) asm volatile("s_waitcnt vmcnt(4)" ::: "memory");
            else if (wcnt == 0) asm volatile("s_waitcnt vmcnt(0)" ::: "memory");
            __builtin_amdgcn_s_barrier();
            __builtin_amdgcn_sched_barrier(0);
        };

#pragma unroll 1
        for (int it = 0; it < 7; ++it) {
            int sb = it * 4;
#pragma unroll
            for (int q = 0; q < 4; ++q) {
                phase(sb + q, 0, true, -1);
                phase(sb + q, 1, true, 6);
            }
        }
        // tail: K-steps 28..31 (stages A31,B31 only; waits 6,4,0)
        phase(28, 0, true,  -1);
        phase(28, 1, true,   6);
        phase(29, 0, false, -1);
        phase(29, 1, false,  4);
        phase(30, 0, false, -1);
        phase(30, 1, false,  0);
        phase(31, 0, false, -1);
        phase(31, 1, false, -1);

        // epilogue: D row=(lane>>4)*4+r, col=lane&15 [m89]
        const int colc = n0 + wn * 64 + (lane & 15);
        float bev[4];
#pragma unroll
        for (int ni = 0; ni < 4; ++ni) bev[ni] = be[e * DH + colc + ni * 16];
        const int rb = m0 + wm * 128 + (lane >> 4) * 4;
#pragma unroll
        for (int mi = 0; mi < 8; ++mi) {
#pragma unroll
            for (int r = 0; r < 4; ++r) {
                int tk = perm[rb + mi * 16 + r];
                if (e_lo == e_hi || eidx[tk] == e) {
                    float* orow = out + (size_t)tk * DH + colc;
#pragma unroll
                    for (int ni = 0; ni < 4; ++ni)
                        orow[ni * 16] = acc[mi][ni][r] + bev[ni];
                }
            }
        }
    }
}

extern "C" void kernel_launch(void* const* d_in, const int* in_sizes, int n_in,
                              void* d_out, int out_size, void* d_ws, size_t ws_size,
                              hipStream_t stream) {
    const float* x  = (const float*)d_in[0];
    const float* Wg = (const float*)d_in[1];
    const float* bg = (const float*)d_in[2];
    const float* We = (const float*)d_in[3];
    const float* be = (const float*)d_in[4];
    float* out = (float*)d_out;
    int T = in_sizes[0] / DM;   // 16384

    char* ws = (char*)d_ws;
    int* cur  = (int*)ws;
    int* perm = (int*)(ws + 4096);
    int* eidx = (int*)(ws + 4096 + 65536);
    unsigned short* webt = (unsigned short*)(ws + 4096 + 2 * 65536);
    unsigned short* xbf  = (unsigned short*)(ws + 4096 + 2 * 65536 + (size_t)2 * DH * DM * 2);

    hipMemsetAsync(cur, 0, 8, stream);
    hipLaunchKernelGGL(prep, dim3(512 + T / 64), dim3(1024), 0, stream,
                       x, Wg, bg, We, T, xbf, webt, perm, eidx, cur);
    int nblk = (T / 256) * (DH / 256);   // 64 * 16 = 1024
    hipLaunchKernelGGL(moe_gemm, dim3(nblk), dim3(512), 0, stream,
                       xbf, webt, be, perm, eidx, out);
}

// Round 5
// 223.746 us; speedup vs baseline: 2.2833x; 1.1283x over previous
//
#include <hip/hip_runtime.h>
#include <hip/hip_bf16.h>

// MoE top-1, E=2: out[t,:] = x[t,:] @ We[e*] + be[e*],  e* = argmax(x[t]@Wg + bg)
//
// moe_gemm: m97-verified structure — 128x128 tile, BK=32, 4 waves (2x2),
// single LDS buffer, 2 __syncthreads per K-step, global_load_lds width-16,
// T2 swizzle f(row)=(row>>1)&3 (R2/R4-verified zero-conflict), XCD swizzle.
// Epilogue: LDS-transpose (stride 68 f32) -> 4-rows-x-256B-contiguous
// nontemporal float4 stores (full 64B lines, no RFO, no L3 pollution).

#define DM 1024
#define DH 4096
#define KS 32
#define NS (DM / KS)   // 32 K-steps

typedef __attribute__((ext_vector_type(4))) float f32x4;
typedef __attribute__((ext_vector_type(8))) __bf16 bf16x8;

__device__ __forceinline__ unsigned short f2bf(float f) {
    union { float f; unsigned u; } a; a.f = f;
    unsigned u = a.u;
    u += 0x7fffu + ((u >> 16) & 1u);   // RNE
    return (unsigned short)(u >> 16);
}

__device__ __forceinline__ void gl16(const unsigned short* g, unsigned short* l) {
    __builtin_amdgcn_global_load_lds(
        (const __attribute__((address_space(1))) unsigned int*)(g),
        (__attribute__((address_space(3))) unsigned int*)(l), 16, 0, 0);
}

// ---------------- prep: We transpose (bid<512) | gate+convert+scatter (bid>=512) ----------------
__global__ __launch_bounds__(1024) void prep(
    const float* __restrict__ x, const float* __restrict__ Wg,
    const float* __restrict__ bg, const float* __restrict__ We, int T,
    unsigned short* __restrict__ xbf, unsigned short* __restrict__ webt,
    int* __restrict__ perm, int* __restrict__ eidx, int* __restrict__ cur)
{
    int bid = blockIdx.x, tid = threadIdx.x;

    if (bid < 512) {
        // ---- We [2][1024][4096] f32 -> webt [2][4096][1024] bf16, 4 64x64 tiles/block ----
        __shared__ unsigned short tile[4][64][72];
        int sub = tid >> 8, t2 = tid & 255;
        int g = bid * 4 + sub;
        int e = g >> 10, rr = g & 1023, kt = rr >> 6, ht = rr & 63;
        int k0 = kt * 64, h0 = ht * 64;
        int k = t2 >> 2, hc = t2 & 3;
        const float* src = We + ((size_t)e * DM + k0 + k) * DH + h0 + hc * 16;
#pragma unroll
        for (int j = 0; j < 4; ++j) {
            f32x4 v = *(const f32x4*)(src + j * 4);
#pragma unroll
            for (int q = 0; q < 4; ++q)
                tile[sub][hc * 16 + j * 4 + q][k] = f2bf(v[q]);
        }
        __syncthreads();
        int h = t2 >> 2, kc = t2 & 3;
        unsigned short* dst = webt + ((size_t)e * DH + h0 + h) * DM + k0 + kc * 16;
        *(uint4*)(dst)     = *(const uint4*)&tile[sub][h][kc * 16];
        *(uint4*)(dst + 8) = *(const uint4*)&tile[sub][h][kc * 16 + 8];
        return;
    }

    // ---- gate: 64 tokens/block, 16 waves x 4 tokens; 2 atomics/block (G12) ----
    __shared__ unsigned char eL[64];
    int gb = bid - 512;                 // 0..255
    int lane = tid & 63, w = tid >> 6;  // 16 waves
    float wgv[32];                      // Wg rows 2c,2c+1 for this lane's 16 cols
#pragma unroll
    for (int j = 0; j < 8; ++j)
        *(f32x4*)&wgv[j * 4] = *(const f32x4*)(Wg + lane * 32 + j * 4);
    float bg0 = bg[0], bg1 = bg[1];
    int t0 = gb * 64 + w * 4;
#pragma unroll
    for (int tl = 0; tl < 4; ++tl) {
        int t = t0 + tl;
        const float* xr = x + (size_t)t * DM + lane * 16;
        double g0 = 0.0, g1 = 0.0;
        unsigned hw[8];
#pragma unroll
        for (int j = 0; j < 4; ++j) {
            f32x4 v = *(const f32x4*)(xr + j * 4);
#pragma unroll
            for (int q = 0; q < 4; ++q) {
                g0 += (double)v[q] * (double)wgv[2 * (j * 4 + q)];
                g1 += (double)v[q] * (double)wgv[2 * (j * 4 + q) + 1];
            }
            hw[j * 2]     = (unsigned)f2bf(v[0]) | ((unsigned)f2bf(v[1]) << 16);
            hw[j * 2 + 1] = (unsigned)f2bf(v[2]) | ((unsigned)f2bf(v[3]) << 16);
        }
        unsigned short* xw = xbf + (size_t)t * DM + lane * 16;
        uint4 u0; u0.x = hw[0]; u0.y = hw[1]; u0.z = hw[2]; u0.w = hw[3];
        uint4 u1; u1.x = hw[4]; u1.y = hw[5]; u1.z = hw[6]; u1.w = hw[7];
        *(uint4*)(xw)     = u0;
        *(uint4*)(xw + 8) = u1;
#pragma unroll
        for (int off = 32; off; off >>= 1) {
            g0 += __shfl_xor(g0, off);
            g1 += __shfl_xor(g1, off);
        }
        if (lane == 0) {
            int ee = ((g1 + (double)bg1) > (g0 + (double)bg0)) ? 1 : 0;  // tie -> e0
            eidx[t] = ee;
            eL[w * 4 + tl] = (unsigned char)ee;
        }
    }
    __syncthreads();
    if (w == 0) {
        int myE = eL[lane];
        unsigned long long m1 = __ballot(myE != 0);
        int tot1 = __popcll(m1);
        int b0 = 0, b1 = 0;
        if (lane == 0) {
            b0 = atomicAdd(cur, 64 - tot1);
            b1 = atomicAdd(cur + 1, tot1);
        }
        b0 = __shfl(b0, 0);
        b1 = __shfl(b1, 0);
        unsigned long long lm = (1ull << lane) - 1ull;
        int rank = __popcll((myE ? m1 : ~m1) & lm);
        int dstp = myE ? (T - b1 - tot1 + rank) : (b0 + rank);
        perm[dstp] = gb * 64 + lane;
    }
}

// ---------------- grouped GEMM, m97 structure ----------------
__global__ __launch_bounds__(256, 3) void moe_gemm(
    const unsigned short* __restrict__ xbf,
    const unsigned short* __restrict__ webt,
    const float* __restrict__ be,
    const int* __restrict__ perm,
    const int* __restrict__ eidx,
    float* __restrict__ out)
{
    __shared__ __align__(16) char smem[17408];           // 17.4 KB: staging | epilogue
    unsigned short* As = (unsigned short*)smem;          // 8 KB (128x32 bf16)
    unsigned short* Bs = (unsigned short*)(smem + 8192); // 8 KB

    const int nwg = gridDim.x;                           // 4096, %8==0
    const int bid = blockIdx.x;
    const int swz = (bid & 7) * (nwg >> 3) + (bid >> 3); // XCD swizzle
    const int mt = swz >> 5, nt = swz & 31;              // 128 m-tiles x 32 n-tiles
    const int m0 = mt * 128, n0 = nt * 128;
    const int tid = threadIdx.x, lane = tid & 63, wid = tid >> 6;
    const int wm = wid >> 1, wn = wid & 1;

    // staging: 512 granules(16B) per operand; granule c=[row=c>>2][phys=c&3],
    // source k8 = phys ^ ((row>>1)&3)  (inverse swizzle on SOURCE, linear LDS dest)
    const unsigned short *aptr0, *aptr1;
    size_t bofs0, bofs1;
    {
        int c0 = tid, c1 = tid + 256;
        int r0 = c0 >> 2, k80 = (c0 & 3) ^ ((r0 >> 1) & 3);
        int r1 = c1 >> 2, k81 = (c1 & 3) ^ ((r1 >> 1) & 3);
        aptr0 = xbf + (size_t)perm[m0 + r0] * DM + k80 * 8;
        aptr1 = xbf + (size_t)perm[m0 + r1] * DM + k81 * 8;
        bofs0 = (size_t)(n0 + r0) * DM + k80 * 8;
        bofs1 = (size_t)(n0 + r1) * DM + k81 * 8;
    }

    // fragment read offsets: slot = (lane>>4) ^ ((row>>1)&3); invariant over mi/ni (rows step 16)
    const int rA = wm * 64 + (lane & 15);
    const int rB = wn * 64 + (lane & 15);
    const int offA = rA * KS + (((lane >> 4) ^ ((rA >> 1) & 3)) * 8);
    const int offB = rB * KS + (((lane >> 4) ^ ((rB >> 1) & 3)) * 8);

    const int e_lo = eidx[perm[m0]];
    const int e_hi = eidx[perm[m0 + 127]];

    for (int e = e_lo; e <= e_hi; ++e) {
        const unsigned short* wb = webt + (size_t)e * DH * DM;

        f32x4 acc[4][4];
#pragma unroll
        for (int mi = 0; mi < 4; ++mi)
#pragma unroll
            for (int ni = 0; ni < 4; ++ni) acc[mi][ni] = 0.f;

#pragma unroll 1
        for (int kt = 0; kt < NS; ++kt) {
            __syncthreads();                       // prev tile's readers done
            gl16(aptr0 + kt * KS, As + tid * 8);
            gl16(aptr1 + kt * KS, As + (tid + 256) * 8);
            gl16(wb + bofs0 + kt * KS, Bs + tid * 8);
            gl16(wb + bofs1 + kt * KS, Bs + (tid + 256) * 8);
            __syncthreads();                       // compiler drains vmcnt before barrier

            bf16x8 af[4], bfr[4];
#pragma unroll
            for (int mi = 0; mi < 4; ++mi) af[mi] = *(const bf16x8*)(As + offA + mi * 16 * KS);
#pragma unroll
            for (int ni = 0; ni < 4; ++ni) bfr[ni] = *(const bf16x8*)(Bs + offB + ni * 16 * KS);
#pragma unroll
            for (int mi = 0; mi < 4; ++mi)
#pragma unroll
                for (int ni = 0; ni < 4; ++ni)
                    acc[mi][ni] = __builtin_amdgcn_mfma_f32_16x16x32_bf16(
                        af[mi], bfr[ni], acc[mi][ni], 0, 0, 0);
        }

        // ---- epilogue: LDS transpose -> wide nontemporal stores ----
        __syncthreads();                           // all waves done reading As/Bs
        float* ep = (float*)smem + wid * (16 * 68);   // per-wave 16x64 f32, stride 68
        const int colb = n0 + wn * 64;
        float bev[4];
#pragma unroll
        for (int ni = 0; ni < 4; ++ni) bev[ni] = be[e * DH + colb + ni * 16 + (lane & 15)];
        const bool multi = (e_lo != e_hi);
        const int rowb = m0 + wm * 64;

#pragma unroll
        for (int mi = 0; mi < 4; ++mi) {
            // scatter acc (D layout: row=(lane>>4)*4+r, col=ni*16+(lane&15)) into ep
#pragma unroll
            for (int ni = 0; ni < 4; ++ni)
#pragma unroll
                for (int r = 0; r < 4; ++r)
                    ep[((lane >> 4) * 4 + r) * 68 + ni * 16 + (lane & 15)] =
                        acc[mi][ni][r] + bev[ni];
            // gather contiguous: lane -> row g*4+(lane>>4), cols (lane&15)*4..+4
#pragma unroll
            for (int g = 0; g < 4; ++g) {
                f32x4 v = *(const f32x4*)&ep[(g * 4 + (lane >> 4)) * 68 + (lane & 15) * 4];
                int tk = perm[rowb + mi * 16 + g * 4 + (lane >> 4)];
                if (!multi || eidx[tk] == e)
                    __builtin_nontemporal_store(
                        v, (f32x4*)(out + (size_t)tk * DH + colb + (lane & 15) * 4));
            }
        }
        // loop-top __syncthreads() (next e) protects ep before restaging
    }
}

extern "C" void kernel_launch(void* const* d_in, const int* in_sizes, int n_in,
                              void* d_out, int out_size, void* d_ws, size_t ws_size,
                              hipStream_t stream) {
    const float* x  = (const float*)d_in[0];
    const float* Wg = (const float*)d_in[1];
    const float* bg = (const float*)d_in[2];
    const float* We = (const float*)d_in[3];
    const float* be = (const float*)d_in[4];
    float* out = (float*)d_out;
    int T = in_sizes[0] / DM;   // 16384

    char* ws = (char*)d_ws;
    int* cur  = (int*)ws;
    int* perm = (int*)(ws + 4096);
    int* eidx = (int*)(ws + 4096 + 65536);
    unsigned short* webt = (unsigned short*)(ws + 4096 + 2 * 65536);
    unsigned short* xbf  = (unsigned short*)(ws + 4096 + 2 * 65536 + (size_t)2 * DH * DM * 2);

    hipMemsetAsync(cur, 0, 8, stream);
    hipLaunchKernelGGL(prep, dim3(512 + T / 64), dim3(1024), 0, stream,
                       x, Wg, bg, We, T, xbf, webt, perm, eidx, cur);
    int nblk = (T / 128) * (DH / 128);   // 128 * 32 = 4096
    hipLaunchKernelGGL(moe_gemm, dim3(nblk), dim3(256), 0, stream,
                       xbf, webt, be, perm, eidx, out);
}